// Round 16
// baseline (232.271 us; speedup 1.0000x reference)
//
#include <hip/hip_runtime.h>
#include <hip/hip_bf16.h>
#include <math.h>

// Problem constants
#define NN 30000
#define NE 480000
#define FIN 256
#define DH 32
#define NH 4
#define NC 47
#define NODE_BLKS 7500   // NN/4 (4 waves/block, 1 wave/node)
#define EDGE_BLKS 1875   // NE/256
#define SCAN_CHUNK 1024  // 30 chunks of 1024 (30720 >= 30000)
#define NCHUNKS 30

typedef __attribute__((ext_vector_type(8))) short frag_ab;  // 8 bf16 (4 VGPR)
typedef __attribute__((ext_vector_type(4))) float f32x4;    // MFMA 16x16 accum
typedef __hip_bfloat16 bf16;

static inline size_t align256(size_t x) { return (x + 255) & ~(size_t)255; }

__device__ __forceinline__ short f2bf(float f) {
    union { float f; unsigned u; } c; c.f = f;
    unsigned r = (c.u + 0x7FFFu + ((c.u >> 16) & 1u)) >> 16;  // RNE
    return (short)r;
}
__device__ __forceinline__ float b2f(unsigned short u) {
    union { unsigned u; float f; } c; c.u = (unsigned)u << 16; return c.f;
}
// exp(leaky_relu(v)) — no max subtraction (scores O(10), far from f32 overflow)
__device__ __forceinline__ float expw(float v) {
    return __expf((v >= 0.f) ? v : 0.2f * v);
}
__device__ __forceinline__ float lrelu(float v) {
    return (v >= 0.f) ? v : 0.2f * v;
}

// ---- weight prep (y<5) ∥ CSR count+rank (y==5). cnt zeroed beforehand.
// rank[e] = this edge's arrival index among edges with the same dst.
// Layout: rows 0..Msrc-1 = W^T; rows Mpad..Mpad+H-1 = W·al; next H = W·ar; rest 0.
__global__ void prep_count(const float* __restrict__ W0, const float* __restrict__ W1,
                           const float* __restrict__ rW1, const float* __restrict__ W2,
                           const float* __restrict__ rW2,
                           const float* __restrict__ al0, const float* __restrict__ ar0,
                           const float* __restrict__ al1, const float* __restrict__ ar1,
                           const float* __restrict__ al2, const float* __restrict__ ar2,
                           bf16* __restrict__ W0t, bf16* __restrict__ W1t,
                           bf16* __restrict__ rW1t, bf16* __restrict__ W2t,
                           bf16* __restrict__ rW2t,
                           const int* __restrict__ dst, int* __restrict__ cnt,
                           int* __restrict__ rank) {
    if (blockIdx.y == 5) {   // edge count + rank
        int e = blockIdx.x * 256 + threadIdx.x;
        if (e < NE) rank[e] = atomicAdd(&cnt[dst[e]], 1);
        return;
    }
    const float *W, *al, *ar; bf16* Wt; int K, Msrc, Mpad, rows, H, D;
    switch (blockIdx.y) {
        case 0: W = W0;  Wt = W0t;  K = 256; Msrc = 128; Mpad = 128; rows = 144; H = 4; D = 32; al = al0; ar = ar0; break;
        case 1: W = W1;  Wt = W1t;  K = 128; Msrc = 128; Mpad = 128; rows = 144; H = 4; D = 32; al = al1; ar = ar1; break;
        case 2: W = rW1; Wt = rW1t; K = 128; Msrc = 128; Mpad = 128; rows = 128; H = 0; D = 0;  al = nullptr; ar = nullptr; break;
        case 3: W = W2;  Wt = W2t;  K = 128; Msrc = 47;  Mpad = 48;  rows = 64;  H = 1; D = 47; al = al2; ar = ar2; break;
        default: W = rW2; Wt = rW2t; K = 128; Msrc = 47; Mpad = 48;  rows = 48;  H = 0; D = 0;  al = nullptr; ar = nullptr; break;
    }
    int i = blockIdx.x * 256 + threadIdx.x;
    if (i >= rows * K) return;
    int row = i / K, k = i - row * K;
    float v = 0.f;
    if (row < Msrc) {
        v = W[(long)k * Msrc + row];
    } else if (H > 0 && row >= Mpad && row < Mpad + 2 * H) {
        int idx = row - Mpad;
        int h = (idx < H) ? idx : idx - H;
        const float* a = (idx < H) ? al : ar;
        float s = 0.f;
        for (int d = 0; d < D; ++d) s += W[(long)k * Msrc + h * D + d] * a[h * D + d];
        v = s;
    }
    Wt[i] = __float2bfloat16(v);
}

// ---- bf16 MFMA GEMM + fused attn projections, with optional tail blocks ----
// TAIL=0: none.
// TAIL=1: scanA chunks (blocks [nG, nG+NCHUNKS)) + fill blocks (>= nG+NCHUNKS,
//   spin on t_ready then scatter srcs). In-dispatch publish protocol:
//   each chunk: loff stores -> __syncthreads -> tid0 fence + atomicAdd(done);
//   last chunk: writes bases -> fence -> release-store t_ready=1.
// TAIL=2: e-score writer for a PREVIOUS layer (H=4 float4 tables pel/per -> eout).
template <bool A_F32, int NT1, int NT2, int HH, int TAIL>
__global__ __launch_bounds__(256) void gemm_mfma(
    const void* __restrict__ Av, const bf16* __restrict__ B1t,
    const bf16* __restrict__ B2t,
    bf16* __restrict__ C1b, float* __restrict__ el, float* __restrict__ er,
    bf16* __restrict__ C2, int N, int K, int M, int nGemmBlocks,
    const int* __restrict__ t_cnt, int* __restrict__ t_loff, int* __restrict__ t_bsum,
    int* __restrict__ t_bases, int* __restrict__ t_done, int* __restrict__ t_ready,
    const int* __restrict__ rank, int* __restrict__ srcs,
    const float4* __restrict__ pel, const float4* __restrict__ per,
    const int* __restrict__ src, const int* __restrict__ dst,
    float* __restrict__ eout) {
    constexpr int LP = 56;  // 32 k + pad: rows 112B (16B-aligned, 2-way alias = free)
    __shared__ bf16 As[64][LP];
    __shared__ bf16 Bs1[NT1 * 16][LP];
    __shared__ bf16 Bs2[(NT2 > 0) ? NT2 * 16 : 1][LP];
    __shared__ int ws4[4];

    const int tid = threadIdx.x;

    if constexpr (TAIL == 1) {
        if (blockIdx.x >= nGemmBlocks + NCHUNKS) {
            // ---- fill tail: wait for scan publish, then atomic-free scatter ----
            if (tid == 0) {
                while (__hip_atomic_load(t_ready, __ATOMIC_ACQUIRE,
                                         __HIP_MEMORY_SCOPE_AGENT) == 0) {}
            }
            __syncthreads();
            const int e = (blockIdx.x - nGemmBlocks - NCHUNKS) * 256 + tid;  // exact NE
            const int d = dst[e];
            srcs[t_loff[d] + t_bases[d >> 10] + rank[e]] = src[e];
            return;
        }
        if (blockIdx.x >= nGemmBlocks) {
            // ---- scanA chunk: local exclusive scan (256 thr x 4 elems) ----
            const int chunk = blockIdx.x - nGemmBlocks;
            const int lane = tid & 63;
            const int wid = tid >> 6;
            const int g = chunk * SCAN_CHUNK + tid * 4;
            const int a0 = (g + 0 < NN) ? t_cnt[g + 0] : 0;
            const int a1 = (g + 1 < NN) ? t_cnt[g + 1] : 0;
            const int a2 = (g + 2 < NN) ? t_cnt[g + 2] : 0;
            const int a3 = (g + 3 < NN) ? t_cnt[g + 3] : 0;
            const int lsum = a0 + a1 + a2 + a3;
            int x = lsum;
            #pragma unroll
            for (int off = 1; off < 64; off <<= 1) {
                int y = __shfl_up(x, off);
                if (lane >= off) x += y;
            }
            if (lane == 63) ws4[wid] = x;
            __syncthreads();
            int wbase = 0;
            #pragma unroll
            for (int j = 0; j < 4; ++j) if (j < wid) wbase += ws4[j];
            const int excl = wbase + x - lsum;
            if (g + 0 < NN) t_loff[g + 0] = excl;
            if (g + 1 < NN) t_loff[g + 1] = excl + a0;
            if (g + 2 < NN) t_loff[g + 2] = excl + a0 + a1;
            if (g + 3 < NN) t_loff[g + 3] = excl + a0 + a1 + a2;
            __syncthreads();   // all loff stores in this block precede the publish
            if (tid == 0) {
                t_bsum[chunk] = ws4[0] + ws4[1] + ws4[2] + ws4[3];
                __threadfence();                       // publish bsum + loff
                const int prev = atomicAdd(t_done, 1);
                if (prev == NCHUNKS - 1) {             // last chunk: scan bases
                    __threadfence();                   // acquire others' bsum
                    int acc = 0;
                    for (int j = 0; j < NCHUNKS; ++j) { t_bases[j] = acc; acc += t_bsum[j]; }
                    t_bases[NCHUNKS] = acc;
                    __threadfence();                   // publish bases
                    __hip_atomic_store(t_ready, 1, __ATOMIC_RELEASE,
                                       __HIP_MEMORY_SCOPE_AGENT);
                }
            }
            return;
        }
    }
    if constexpr (TAIL == 2) {
        if (blockIdx.x >= nGemmBlocks) {
            const int e = (blockIdx.x - nGemmBlocks) * 256 + tid;  // exact NE grid
            const int s = src[e], d = dst[e];
            const float4 a = pel[s], b = per[d];
            float4 v;
            v.x = lrelu(a.x + b.x); v.y = lrelu(a.y + b.y);
            v.z = lrelu(a.z + b.z); v.w = lrelu(a.w + b.w);
            *reinterpret_cast<float4*>(eout + e * 4) = v;
            return;
        }
    }

    const int lane = tid & 63;
    const int wid = tid >> 6;
    const int row0 = blockIdx.x * 64;
    const int l15 = lane & 15;
    const int kq = lane >> 4;          // k-quarter 0..3

    f32x4 acc1[NT1], acc2[(NT2 > 0) ? NT2 : 1];
    #pragma unroll
    for (int t = 0; t < NT1; ++t) acc1[t] = (f32x4){0.f, 0.f, 0.f, 0.f};
    if constexpr (NT2 > 0) {
        #pragma unroll
        for (int t = 0; t < NT2; ++t) acc2[t] = (f32x4){0.f, 0.f, 0.f, 0.f};
    }

    for (int k0 = 0; k0 < K; k0 += 32) {
        {
            const int r = tid >> 2, kk = (tid & 3) * 8;
            const int gr = row0 + r;
            if constexpr (A_F32) {
                const float* A = (const float*)Av;
                short tmp[8];
                if (gr < N) {
                    const float4 v0 = *(const float4*)&A[(long)gr * K + k0 + kk];
                    const float4 v1 = *(const float4*)&A[(long)gr * K + k0 + kk + 4];
                    tmp[0] = f2bf(v0.x); tmp[1] = f2bf(v0.y); tmp[2] = f2bf(v0.z); tmp[3] = f2bf(v0.w);
                    tmp[4] = f2bf(v1.x); tmp[5] = f2bf(v1.y); tmp[6] = f2bf(v1.z); tmp[7] = f2bf(v1.w);
                } else {
                    #pragma unroll
                    for (int j = 0; j < 8; ++j) tmp[j] = 0;
                }
                *(frag_ab*)&As[r][kk] = *(const frag_ab*)tmp;
            } else {
                const bf16* A = (const bf16*)Av;
                frag_ab v = {0, 0, 0, 0, 0, 0, 0, 0};
                if (gr < N) v = *(const frag_ab*)&A[(long)gr * K + k0 + kk];
                *(frag_ab*)&As[r][kk] = v;
            }
        }
        for (int i = tid; i < NT1 * 64; i += 256) {
            const int c = i >> 2, kk = (i & 3) * 8;
            *(frag_ab*)&Bs1[c][kk] = *(const frag_ab*)&B1t[(long)c * K + k0 + kk];
        }
        if constexpr (NT2 > 0) {
            for (int i = tid; i < NT2 * 64; i += 256) {
                const int c = i >> 2, kk = (i & 3) * 8;
                *(frag_ab*)&Bs2[c][kk] = *(const frag_ab*)&B2t[(long)c * K + k0 + kk];
            }
        }
        __syncthreads();

        const frag_ab a = *(const frag_ab*)&As[wid * 16 + l15][kq * 8];
        #pragma unroll
        for (int t = 0; t < NT1; ++t) {
            const frag_ab b = *(const frag_ab*)&Bs1[t * 16 + l15][kq * 8];
            acc1[t] = __builtin_amdgcn_mfma_f32_16x16x32_bf16(a, b, acc1[t], 0, 0, 0);
        }
        if constexpr (NT2 > 0) {
            #pragma unroll
            for (int t = 0; t < NT2; ++t) {
                const frag_ab b = *(const frag_ab*)&Bs2[t * 16 + l15][kq * 8];
                acc2[t] = __builtin_amdgcn_mfma_f32_16x16x32_bf16(a, b, acc2[t], 0, 0, 0);
            }
        }
        __syncthreads();
    }

    const int r0 = row0 + wid * 16 + kq * 4;
    #pragma unroll
    for (int t = 0; t < NT1; ++t) {
        const int c = t * 16 + l15;
        #pragma unroll
        for (int reg = 0; reg < 4; ++reg) {
            const int r = r0 + reg;
            if (r >= N) continue;
            const float v = acc1[t][reg];
            if (c < M) {
                C1b[(long)r * M + c] = __float2bfloat16(v);
            } else if (c < M + HH) {
                el[(long)r * HH + (c - M)] = v;
            } else if (c < M + 2 * HH) {
                er[(long)r * HH + (c - M - HH)] = v;
            }
        }
    }
    if constexpr (NT2 > 0) {
        #pragma unroll
        for (int t = 0; t < NT2; ++t) {
            const int c = t * 16 + l15;
            if (c >= M) continue;
            #pragma unroll
            for (int reg = 0; reg < 4; ++reg) {
                const int r = r0 + reg;
                if (r < N) C2[(long)r * M + c] = __float2bfloat16(acc2[t][reg]);
            }
        }
    }
}

// ---- node softmax + aggregation, SINGLE PASS, one wave/node, H=4 D=32 ----
// Quarter-wave per edge; score computed inline (one wave-instr per 4 edges).
// Main loop: 4 edges per quarter in flight (16 edges/wave-iter).
template <int NELU, bool HAS_RES>
__global__ __launch_bounds__(256) void node_agg4(
    const bf16* __restrict__ featb, const float* __restrict__ el,
    const float4* __restrict__ er4,
    const int* __restrict__ loff, const int* __restrict__ bases,
    const int* __restrict__ srcs,
    const bf16* __restrict__ res, bf16* __restrict__ out) {
    const int node = (int)((blockIdx.x * blockDim.x + threadIdx.x) >> 6);
    const int lane = threadIdx.x & 63;
    const int beg = loff[node] + bases[node >> 10];
    const int end = (node == NN - 1) ? NE : loff[node + 1] + bases[(node + 1) >> 10];

    const int q = lane >> 4;          // quarter 0..3 (edge slot)
    const int l15 = lane & 15;
    const int fi = l15 * 8;           // 8 consecutive features (same head: 8|32)
    const int h = l15 >> 2;           // fi / 32
    const float4 ern4 = er4[node];    // wave-uniform
    const float ern = (h == 0) ? ern4.x : (h == 1) ? ern4.y : (h == 2) ? ern4.z : ern4.w;

    float a[8] = {0.f, 0.f, 0.f, 0.f, 0.f, 0.f, 0.f, 0.f};
    float sl = 0.f;
    int i = beg + q;
    for (; i + 12 < end; i += 16) {   // 4 edges per quarter in flight
        const int s0 = srcs[i], s1 = srcs[i + 4], s2 = srcs[i + 8], s3 = srcs[i + 12];
        const float w0 = expw(el[s0 * 4 + h] + ern);
        const float w1 = expw(el[s1 * 4 + h] + ern);
        const float w2 = expw(el[s2 * 4 + h] + ern);
        const float w3 = expw(el[s3 * 4 + h] + ern);
        sl += (w0 + w1) + (w2 + w3);
        const frag_ab f0 = *(const frag_ab*)(featb + (long)s0 * 128 + fi);
        const frag_ab f1 = *(const frag_ab*)(featb + (long)s1 * 128 + fi);
        const frag_ab f2 = *(const frag_ab*)(featb + (long)s2 * 128 + fi);
        const frag_ab f3 = *(const frag_ab*)(featb + (long)s3 * 128 + fi);
        #pragma unroll
        for (int j = 0; j < 8; ++j)
            a[j] += (w0 * b2f((unsigned short)f0[j]) + w1 * b2f((unsigned short)f1[j]))
                  + (w2 * b2f((unsigned short)f2[j]) + w3 * b2f((unsigned short)f3[j]));
    }
    for (; i + 4 < end; i += 8) {     // 2 in flight
        const int s0 = srcs[i], s1 = srcs[i + 4];
        const float w0 = expw(el[s0 * 4 + h] + ern);
        const float w1 = expw(el[s1 * 4 + h] + ern);
        sl += w0 + w1;
        const frag_ab f0 = *(const frag_ab*)(featb + (long)s0 * 128 + fi);
        const frag_ab f1 = *(const frag_ab*)(featb + (long)s1 * 128 + fi);
        #pragma unroll
        for (int j = 0; j < 8; ++j)
            a[j] += w0 * b2f((unsigned short)f0[j]) + w1 * b2f((unsigned short)f1[j]);
    }
    for (; i < end; i += 4) {
        const int sn = srcs[i];
        const float w = expw(el[sn * 4 + h] + ern);
        sl += w;
        const frag_ab f = *(const frag_ab*)(featb + (long)sn * 128 + fi);
        #pragma unroll
        for (int j = 0; j < 8; ++j) a[j] += w * b2f((unsigned short)f[j]);
    }
    // reduce s and accumulators over the 4 quarters
    sl += __shfl_xor(sl, 16);
    sl += __shfl_xor(sl, 32);
    #pragma unroll
    for (int j = 0; j < 8; ++j) {
        a[j] += __shfl_xor(a[j], 16);
        a[j] += __shfl_xor(a[j], 32);
    }

    if (lane < 16) {
        const float inv = 1.f / fmaxf(sl, 1e-9f);
        float v[8];
        #pragma unroll
        for (int j = 0; j < 8; ++j) v[j] = a[j] * inv;
        if constexpr (HAS_RES) {
            const frag_ab rr = *(const frag_ab*)(res + (long)node * 128 + fi);
            #pragma unroll
            for (int j = 0; j < 8; ++j) v[j] += b2f((unsigned short)rr[j]);
        }
        #pragma unroll
        for (int t = 0; t < NELU; ++t)
            #pragma unroll
            for (int j = 0; j < 8; ++j)
                v[j] = (v[j] > 0.f) ? v[j] : expm1f(v[j]);
        frag_ab o;
        #pragma unroll
        for (int j = 0; j < 8; ++j) o[j] = f2bf(v[j]);
        *(frag_ab*)(out + (long)node * 128 + fi) = o;
    }
}

// ---- final fused kernel: node_agg1 single-pass (blocks < NODE_BLKS) + e2 ----
// Node branch: half-wave per edge; 24 active lanes x ushort2 cover the padded
// 48-feature row (feature 47 == 0 pad).
__global__ __launch_bounds__(256) void final_k(
    const bf16* __restrict__ featb48, const float* __restrict__ el2s,
    const float* __restrict__ er2s,
    const int* __restrict__ loff, const int* __restrict__ bases,
    const int* __restrict__ srcs,
    const bf16* __restrict__ res48, float* __restrict__ logits,
    const int* __restrict__ src, const int* __restrict__ dst,
    float* __restrict__ e2) {
    if (blockIdx.x < NODE_BLKS) {
        const int node = (int)((blockIdx.x * blockDim.x + threadIdx.x) >> 6);
        const int lane = threadIdx.x & 63;
        const int beg = loff[node] + bases[node >> 10];
        const int end = (node == NN - 1) ? NE : loff[node + 1] + bases[(node + 1) >> 10];
        const float ern = er2s[node];

        const int half = lane >> 5;   // 0/1: edge slot
        const int l31 = lane & 31;
        const bool act = l31 < 24;    // 24 lanes x 2 features = 48 (feature 47 = pad)
        const int fi = l31 * 2;

        float a0 = 0.f, a1 = 0.f, sl = 0.f;
        int i = beg + half;
        for (; i + 6 < end; i += 8) {   // 4 edges per half in flight
            const int s0 = srcs[i], s1 = srcs[i + 2], s2 = srcs[i + 4], s3 = srcs[i + 6];
            const float w0 = expw(el2s[s0] + ern);
            const float w1 = expw(el2s[s1] + ern);
            const float w2 = expw(el2s[s2] + ern);
            const float w3 = expw(el2s[s3] + ern);
            sl += (w0 + w1) + (w2 + w3);
            if (act) {
                const ushort2 f0 = *(const ushort2*)(featb48 + (long)s0 * 48 + fi);
                const ushort2 f1 = *(const ushort2*)(featb48 + (long)s1 * 48 + fi);
                const ushort2 f2 = *(const ushort2*)(featb48 + (long)s2 * 48 + fi);
                const ushort2 f3 = *(const ushort2*)(featb48 + (long)s3 * 48 + fi);
                a0 += (w0 * b2f(f0.x) + w1 * b2f(f1.x)) + (w2 * b2f(f2.x) + w3 * b2f(f3.x));
                a1 += (w0 * b2f(f0.y) + w1 * b2f(f1.y)) + (w2 * b2f(f2.y) + w3 * b2f(f3.y));
            }
        }
        for (; i < end; i += 2) {
            const int sn = srcs[i];
            const float w = expw(el2s[sn] + ern);
            sl += w;
            if (act) {
                const ushort2 f = *(const ushort2*)(featb48 + (long)sn * 48 + fi);
                a0 += w * b2f(f.x);
                a1 += w * b2f(f.y);
            }
        }
        // total s: sl is identical across lanes within a half
        const float s = __shfl(sl, 0) + __shfl(sl, 32);
        a0 += __shfl_xor(a0, 32);
        a1 += __shfl_xor(a1, 32);

        if (lane < 24) {
            const float inv = 1.f / fmaxf(s, 1e-9f);
            const ushort2 rr = *(const ushort2*)(res48 + (long)node * 48 + fi);
            const float v0 = a0 * inv + b2f(rr.x);
            const float v1 = a1 * inv + b2f(rr.y);
            logits[(long)node * NC + fi] = v0;
            if (fi + 1 < NC) logits[(long)node * NC + fi + 1] = v1;
        }
    } else {
        const int e = (blockIdx.x - NODE_BLKS) * 256 + threadIdx.x;  // exact NE
        e2[e] = lrelu(el2s[src[e]] + er2s[dst[e]]);
    }
}

extern "C" void kernel_launch(void* const* d_in, const int* in_sizes, int n_in,
                              void* d_out, int out_size, void* d_ws, size_t ws_size,
                              hipStream_t stream) {
    const float* x     = (const float*)d_in[0];
    const float* W0    = (const float*)d_in[1];
    const float* al0   = (const float*)d_in[2];
    const float* ar0   = (const float*)d_in[3];
    const float* W1    = (const float*)d_in[4];
    const float* resW1 = (const float*)d_in[5];
    const float* al1   = (const float*)d_in[6];
    const float* ar1   = (const float*)d_in[7];
    const float* W2    = (const float*)d_in[8];
    const float* resW2 = (const float*)d_in[9];
    const float* al2   = (const float*)d_in[10];
    const float* ar2   = (const float*)d_in[11];
    const int*   src   = (const int*)d_in[12];
    const int*   dst   = (const int*)d_in[13];

    float* out    = (float*)d_out;
    float* logits = out;                 // [N, 47]
    float* e0     = out + (long)NN * NC; // [E, 4]
    float* e1     = e0 + (long)NE * NH;  // [E, 4]
    float* e2     = e1 + (long)NE * NH;  // [E, 1]

    char* p = (char*)d_ws;
    int* cnt    = (int*)p; p += align256(sizeof(int) * (NN + 64));  // cnt + done + ready
    int* done   = cnt + NN;
    int* ready  = cnt + NN + 1;
    int* loff   = (int*)p; p += align256(sizeof(int) * (NN + 1));
    int* bsum   = (int*)p; p += align256(sizeof(int) * 32);
    int* bases  = (int*)p; p += align256(sizeof(int) * 32);
    int* rank   = (int*)p; p += align256(sizeof(int) * NE);
    int* srcs   = (int*)p; p += align256(sizeof(int) * NE);
    float* el0b = (float*)p; p += align256(sizeof(float) * NN * NH);
    float* er0b = (float*)p; p += align256(sizeof(float) * NN * NH);
    float* el1b = (float*)p; p += align256(sizeof(float) * NN * NH);
    float* er1b = (float*)p; p += align256(sizeof(float) * NN * NH);
    float* el2b = (float*)p; p += align256(sizeof(float) * NN);
    float* er2b = (float*)p; p += align256(sizeof(float) * NN);
    bf16* resb  = (bf16*)p; p += align256(sizeof(bf16) * (long)NN * 128);
    bf16* featb = (bf16*)p; p += align256(sizeof(bf16) * (long)NN * 128);
    bf16* hb    = (bf16*)p; p += align256(sizeof(bf16) * (long)NN * 128);
    bf16* W0t   = (bf16*)p; p += align256(sizeof(bf16) * 144 * 256);
    bf16* W1t   = (bf16*)p; p += align256(sizeof(bf16) * 144 * 128);
    bf16* rW1t  = (bf16*)p; p += align256(sizeof(bf16) * 128 * 128);
    bf16* W2t   = (bf16*)p; p += align256(sizeof(bf16) * 64 * 128);
    bf16* rW2t  = (bf16*)p; p += align256(sizeof(bf16) * 48 * 128);

    const int gemmBlocks = (NN + 63) / 64;   // 469

    // ---- 1: zero cnt+done+ready; 2: prep weights ∥ count+rank ----
    hipMemsetAsync(cnt, 0, sizeof(int) * (NN + 64), stream);
    prep_count<<<dim3(EDGE_BLKS, 6), 256, 0, stream>>>(
        W0, W1, resW1, W2, resW2, al0, ar0, al1, ar1, al2, ar2,
        W0t, W1t, rW1t, W2t, rW2t, dst, cnt, rank);

    // ---- 3: gemm0 ∥ scanA ∥ fill (scan publishes in-dispatch; fill spin-waits) ----
    gemm_mfma<true, 9, 0, NH, 1><<<gemmBlocks + NCHUNKS + EDGE_BLKS, 256, 0, stream>>>(
        x, W0t, nullptr, featb, el0b, er0b, nullptr, NN, FIN, 128, gemmBlocks,
        cnt, loff, bsum, bases, done, ready, rank, srcs,
        nullptr, nullptr, src, dst, nullptr);

    // ---- 4: layer-0 aggregation (single pass) ----
    node_agg4<1, false><<<NODE_BLKS, 256, 0, stream>>>(
        featb, el0b, (const float4*)er0b, loff, bases, srcs, nullptr, hb);

    // ---- 5: gemm1 (dual) ∥ e0 writes ----
    gemm_mfma<false, 9, 8, NH, 2><<<gemmBlocks + EDGE_BLKS, 256, 0, stream>>>(
        hb, W1t, rW1t, featb, el1b, er1b, resb, NN, 128, 128, gemmBlocks,
        nullptr, nullptr, nullptr, nullptr, nullptr, nullptr, nullptr, nullptr,
        (const float4*)el0b, (const float4*)er0b, src, dst, e0);

    // ---- 6: layer-1 aggregation (single pass) ----
    node_agg4<2, true><<<NODE_BLKS, 256, 0, stream>>>(
        featb, el1b, (const float4*)er1b, loff, bases, srcs, resb, hb);

    // ---- 7: gemm2 (dual, padded M=48) ∥ e1 writes ----
    gemm_mfma<false, 4, 3, 1, 2><<<gemmBlocks + EDGE_BLKS, 256, 0, stream>>>(
        hb, W2t, rW2t, featb, el2b, er2b, resb, NN, 128, 48, gemmBlocks,
        nullptr, nullptr, nullptr, nullptr, nullptr, nullptr, nullptr, nullptr,
        (const float4*)el1b, (const float4*)er1b, src, dst, e1);

    // ---- 8: node_agg1 single-pass (logits) ∥ e2 writes ----
    final_k<<<NODE_BLKS + EDGE_BLKS, 256, 0, stream>>>(
        featb, el2b, er2b, loff, bases, srcs, resb, logits, src, dst, e2);
}

// Round 17
// 175.668 us; speedup vs baseline: 1.3222x; 1.3222x over previous
//
#include <hip/hip_runtime.h>
#include <hip/hip_bf16.h>
#include <math.h>

// Problem constants
#define NN 30000
#define NE 480000
#define FIN 256
#define DH 32
#define NH 4
#define NC 47
#define NODE_BLKS 7500   // NN/4 (4 waves/block, 1 wave/node)
#define EDGE_BLKS 1875   // NE/256
#define SCAN_CHUNK 1024  // 30 chunks of 1024 (30720 >= 30000)
#define NCHUNKS 30

typedef __attribute__((ext_vector_type(8))) short frag_ab;  // 8 bf16 (4 VGPR)
typedef __attribute__((ext_vector_type(4))) float f32x4;    // MFMA 16x16 accum
typedef __hip_bfloat16 bf16;

static inline size_t align256(size_t x) { return (x + 255) & ~(size_t)255; }

__device__ __forceinline__ short f2bf(float f) {
    union { float f; unsigned u; } c; c.f = f;
    unsigned r = (c.u + 0x7FFFu + ((c.u >> 16) & 1u)) >> 16;  // RNE
    return (short)r;
}
__device__ __forceinline__ float b2f(unsigned short u) {
    union { unsigned u; float f; } c; c.u = (unsigned)u << 16; return c.f;
}
// exp(leaky_relu(v)) — no max subtraction (scores O(10), far from f32 overflow)
__device__ __forceinline__ float expw(float v) {
    return __expf((v >= 0.f) ? v : 0.2f * v);
}
__device__ __forceinline__ float lrelu(float v) {
    return (v >= 0.f) ? v : 0.2f * v;
}

// ---- weight prep (y<5) ∥ CSR count+rank (y==5). cnt zeroed beforehand.
// rank[e] = this edge's arrival index among edges with the same dst.
// Layout: rows 0..Msrc-1 = W^T; rows Mpad..Mpad+H-1 = W·al; next H = W·ar; rest 0.
// (For gemm2: Msrc=47, Mpad=48 -> row 47 is a zero pad column.)
__global__ void prep_count(const float* __restrict__ W0, const float* __restrict__ W1,
                           const float* __restrict__ rW1, const float* __restrict__ W2,
                           const float* __restrict__ rW2,
                           const float* __restrict__ al0, const float* __restrict__ ar0,
                           const float* __restrict__ al1, const float* __restrict__ ar1,
                           const float* __restrict__ al2, const float* __restrict__ ar2,
                           bf16* __restrict__ W0t, bf16* __restrict__ W1t,
                           bf16* __restrict__ rW1t, bf16* __restrict__ W2t,
                           bf16* __restrict__ rW2t,
                           const int* __restrict__ dst, int* __restrict__ cnt,
                           int* __restrict__ rank) {
    if (blockIdx.y == 5) {   // edge count + rank
        int e = blockIdx.x * 256 + threadIdx.x;
        if (e < NE) rank[e] = atomicAdd(&cnt[dst[e]], 1);
        return;
    }
    const float *W, *al, *ar; bf16* Wt; int K, Msrc, Mpad, rows, H, D;
    switch (blockIdx.y) {
        case 0: W = W0;  Wt = W0t;  K = 256; Msrc = 128; Mpad = 128; rows = 144; H = 4; D = 32; al = al0; ar = ar0; break;
        case 1: W = W1;  Wt = W1t;  K = 128; Msrc = 128; Mpad = 128; rows = 144; H = 4; D = 32; al = al1; ar = ar1; break;
        case 2: W = rW1; Wt = rW1t; K = 128; Msrc = 128; Mpad = 128; rows = 128; H = 0; D = 0;  al = nullptr; ar = nullptr; break;
        case 3: W = W2;  Wt = W2t;  K = 128; Msrc = 47;  Mpad = 48;  rows = 64;  H = 1; D = 47; al = al2; ar = ar2; break;
        default: W = rW2; Wt = rW2t; K = 128; Msrc = 47; Mpad = 48;  rows = 48;  H = 0; D = 0;  al = nullptr; ar = nullptr; break;
    }
    int i = blockIdx.x * 256 + threadIdx.x;
    if (i >= rows * K) return;
    int row = i / K, k = i - row * K;
    float v = 0.f;
    if (row < Msrc) {
        v = W[(long)k * Msrc + row];
    } else if (H > 0 && row >= Mpad && row < Mpad + 2 * H) {
        int idx = row - Mpad;
        int h = (idx < H) ? idx : idx - H;
        const float* a = (idx < H) ? al : ar;
        float s = 0.f;
        for (int d = 0; d < D; ++d) s += W[(long)k * Msrc + h * D + d] * a[h * D + d];
        v = s;
    }
    Wt[i] = __float2bfloat16(v);
}

// srcs[slot] = src id, in CSR-by-dst order. Atomic-free (rank precomputed).
__global__ void fill_k(const int* __restrict__ dst, const int* __restrict__ src,
                       const int* __restrict__ rank, const int* __restrict__ loff,
                       const int* __restrict__ bases, int* __restrict__ srcs) {
    int e = blockIdx.x * blockDim.x + threadIdx.x;
    if (e < NE) {
        const int d = dst[e];
        srcs[loff[d] + bases[d >> 10] + rank[e]] = src[e];
    }
}

// ---- bf16 MFMA GEMM + fused attn projections, with optional tail blocks ----
// TAIL=0: none. TAIL=1: scanA (chunk-local exclusive scan of t_cnt); last
//   finishing chunk scans bsum -> bases (device-scope done counter).
// TAIL=2: e-score writer for a PREVIOUS layer (H=4 float4 tables pel/per -> eout).
template <bool A_F32, int NT1, int NT2, int HH, int TAIL>
__global__ __launch_bounds__(256) void gemm_mfma(
    const void* __restrict__ Av, const bf16* __restrict__ B1t,
    const bf16* __restrict__ B2t,
    bf16* __restrict__ C1b, float* __restrict__ el, float* __restrict__ er,
    bf16* __restrict__ C2, int N, int K, int M, int nGemmBlocks,
    const int* __restrict__ t_cnt, int* __restrict__ t_loff, int* __restrict__ t_bsum,
    int* __restrict__ t_bases, int* __restrict__ t_done,
    const float4* __restrict__ pel, const float4* __restrict__ per,
    const int* __restrict__ src, const int* __restrict__ dst,
    float* __restrict__ eout) {
    constexpr int LP = 56;  // 32 k + pad: rows 112B (16B-aligned, 2-way alias = free)
    __shared__ bf16 As[64][LP];
    __shared__ bf16 Bs1[NT1 * 16][LP];
    __shared__ bf16 Bs2[(NT2 > 0) ? NT2 * 16 : 1][LP];
    __shared__ int ws4[4];

    const int tid = threadIdx.x;

    if constexpr (TAIL == 1) {
        if (blockIdx.x >= nGemmBlocks) {
            // chunk-local exclusive scan: 256 threads x 4 elems
            const int chunk = blockIdx.x - nGemmBlocks;
            const int lane = tid & 63;
            const int wid = tid >> 6;
            const int g = chunk * SCAN_CHUNK + tid * 4;
            const int a0 = (g + 0 < NN) ? t_cnt[g + 0] : 0;
            const int a1 = (g + 1 < NN) ? t_cnt[g + 1] : 0;
            const int a2 = (g + 2 < NN) ? t_cnt[g + 2] : 0;
            const int a3 = (g + 3 < NN) ? t_cnt[g + 3] : 0;
            const int lsum = a0 + a1 + a2 + a3;
            int x = lsum;
            #pragma unroll
            for (int off = 1; off < 64; off <<= 1) {
                int y = __shfl_up(x, off);
                if (lane >= off) x += y;
            }
            if (lane == 63) ws4[wid] = x;
            __syncthreads();
            int wbase = 0;
            #pragma unroll
            for (int j = 0; j < 4; ++j) if (j < wid) wbase += ws4[j];
            const int excl = wbase + x - lsum;
            if (g + 0 < NN) t_loff[g + 0] = excl;
            if (g + 1 < NN) t_loff[g + 1] = excl + a0;
            if (g + 2 < NN) t_loff[g + 2] = excl + a0 + a1;
            if (g + 3 < NN) t_loff[g + 3] = excl + a0 + a1 + a2;
            if (tid == 0) {
                t_bsum[chunk] = ws4[0] + ws4[1] + ws4[2] + ws4[3];
                __threadfence();                       // publish bsum + loff
                const int prev = atomicAdd(t_done, 1);
                if (prev == NCHUNKS - 1) {             // last chunk: scan bases
                    __threadfence();                   // acquire others' bsum
                    int acc = 0;
                    for (int j = 0; j < NCHUNKS; ++j) { t_bases[j] = acc; acc += t_bsum[j]; }
                    t_bases[NCHUNKS] = acc;
                }
            }
            return;
        }
    }
    if constexpr (TAIL == 2) {
        if (blockIdx.x >= nGemmBlocks) {
            const int e = (blockIdx.x - nGemmBlocks) * 256 + tid;  // exact NE grid
            const int s = src[e], d = dst[e];
            const float4 a = pel[s], b = per[d];
            float4 v;
            v.x = lrelu(a.x + b.x); v.y = lrelu(a.y + b.y);
            v.z = lrelu(a.z + b.z); v.w = lrelu(a.w + b.w);
            *reinterpret_cast<float4*>(eout + e * 4) = v;
            return;
        }
    }

    const int lane = tid & 63;
    const int wid = tid >> 6;
    const int row0 = blockIdx.x * 64;
    const int l15 = lane & 15;
    const int kq = lane >> 4;          // k-quarter 0..3

    f32x4 acc1[NT1], acc2[(NT2 > 0) ? NT2 : 1];
    #pragma unroll
    for (int t = 0; t < NT1; ++t) acc1[t] = (f32x4){0.f, 0.f, 0.f, 0.f};
    if constexpr (NT2 > 0) {
        #pragma unroll
        for (int t = 0; t < NT2; ++t) acc2[t] = (f32x4){0.f, 0.f, 0.f, 0.f};
    }

    for (int k0 = 0; k0 < K; k0 += 32) {
        {
            const int r = tid >> 2, kk = (tid & 3) * 8;
            const int gr = row0 + r;
            if constexpr (A_F32) {
                const float* A = (const float*)Av;
                short tmp[8];
                if (gr < N) {
                    const float4 v0 = *(const float4*)&A[(long)gr * K + k0 + kk];
                    const float4 v1 = *(const float4*)&A[(long)gr * K + k0 + kk + 4];
                    tmp[0] = f2bf(v0.x); tmp[1] = f2bf(v0.y); tmp[2] = f2bf(v0.z); tmp[3] = f2bf(v0.w);
                    tmp[4] = f2bf(v1.x); tmp[5] = f2bf(v1.y); tmp[6] = f2bf(v1.z); tmp[7] = f2bf(v1.w);
                } else {
                    #pragma unroll
                    for (int j = 0; j < 8; ++j) tmp[j] = 0;
                }
                *(frag_ab*)&As[r][kk] = *(const frag_ab*)tmp;
            } else {
                const bf16* A = (const bf16*)Av;
                frag_ab v = {0, 0, 0, 0, 0, 0, 0, 0};
                if (gr < N) v = *(const frag_ab*)&A[(long)gr * K + k0 + kk];
                *(frag_ab*)&As[r][kk] = v;
            }
        }
        for (int i = tid; i < NT1 * 64; i += 256) {
            const int c = i >> 2, kk = (i & 3) * 8;
            *(frag_ab*)&Bs1[c][kk] = *(const frag_ab*)&B1t[(long)c * K + k0 + kk];
        }
        if constexpr (NT2 > 0) {
            for (int i = tid; i < NT2 * 64; i += 256) {
                const int c = i >> 2, kk = (i & 3) * 8;
                *(frag_ab*)&Bs2[c][kk] = *(const frag_ab*)&B2t[(long)c * K + k0 + kk];
            }
        }
        __syncthreads();

        const frag_ab a = *(const frag_ab*)&As[wid * 16 + l15][kq * 8];
        #pragma unroll
        for (int t = 0; t < NT1; ++t) {
            const frag_ab b = *(const frag_ab*)&Bs1[t * 16 + l15][kq * 8];
            acc1[t] = __builtin_amdgcn_mfma_f32_16x16x32_bf16(a, b, acc1[t], 0, 0, 0);
        }
        if constexpr (NT2 > 0) {
            #pragma unroll
            for (int t = 0; t < NT2; ++t) {
                const frag_ab b = *(const frag_ab*)&Bs2[t * 16 + l15][kq * 8];
                acc2[t] = __builtin_amdgcn_mfma_f32_16x16x32_bf16(a, b, acc2[t], 0, 0, 0);
            }
        }
        __syncthreads();
    }

    const int r0 = row0 + wid * 16 + kq * 4;
    #pragma unroll
    for (int t = 0; t < NT1; ++t) {
        const int c = t * 16 + l15;
        #pragma unroll
        for (int reg = 0; reg < 4; ++reg) {
            const int r = r0 + reg;
            if (r >= N) continue;
            const float v = acc1[t][reg];
            if (c < M) {
                C1b[(long)r * M + c] = __float2bfloat16(v);
            } else if (c < M + HH) {
                el[(long)r * HH + (c - M)] = v;
            } else if (c < M + 2 * HH) {
                er[(long)r * HH + (c - M - HH)] = v;
            }
        }
    }
    if constexpr (NT2 > 0) {
        #pragma unroll
        for (int t = 0; t < NT2; ++t) {
            const int c = t * 16 + l15;
            if (c >= M) continue;
            #pragma unroll
            for (int reg = 0; reg < 4; ++reg) {
                const int r = r0 + reg;
                if (r < N) C2[(long)r * M + c] = __float2bfloat16(acc2[t][reg]);
            }
        }
    }
}

// ---- node softmax + aggregation, SINGLE PASS, one wave/node, H=4 D=32 ----
// Quarter-wave per edge; score computed inline (one wave-instr per 4 edges).
template <int NELU, bool HAS_RES>
__global__ __launch_bounds__(256) void node_agg4(
    const bf16* __restrict__ featb, const float* __restrict__ el,
    const float4* __restrict__ er4,
    const int* __restrict__ loff, const int* __restrict__ bases,
    const int* __restrict__ srcs,
    const bf16* __restrict__ res, bf16* __restrict__ out) {
    const int node = (int)((blockIdx.x * blockDim.x + threadIdx.x) >> 6);
    const int lane = threadIdx.x & 63;
    const int beg = loff[node] + bases[node >> 10];
    const int end = (node == NN - 1) ? NE : loff[node + 1] + bases[(node + 1) >> 10];

    const int q = lane >> 4;          // quarter 0..3 (edge slot)
    const int l15 = lane & 15;
    const int fi = l15 * 8;           // 8 consecutive features (same head: 8|32)
    const int h = l15 >> 2;           // fi / 32
    const float4 ern4 = er4[node];    // wave-uniform
    const float ern = (h == 0) ? ern4.x : (h == 1) ? ern4.y : (h == 2) ? ern4.z : ern4.w;

    float a[8] = {0.f, 0.f, 0.f, 0.f, 0.f, 0.f, 0.f, 0.f};
    float sl = 0.f;
    int i = beg + q;
    for (; i + 4 < end; i += 8) {
        const int iB = i + 4;
        const int snA = srcs[i], snB = srcs[iB];
        const float wA = expw(el[snA * 4 + h] + ern);
        const float wB = expw(el[snB * 4 + h] + ern);
        sl += wA + wB;
        const frag_ab fA = *(const frag_ab*)(featb + (long)snA * 128 + fi);
        const frag_ab fB = *(const frag_ab*)(featb + (long)snB * 128 + fi);
        #pragma unroll
        for (int j = 0; j < 8; ++j)
            a[j] += wA * b2f((unsigned short)fA[j]) + wB * b2f((unsigned short)fB[j]);
    }
    for (; i < end; i += 4) {
        const int sn = srcs[i];
        const float w = expw(el[sn * 4 + h] + ern);
        sl += w;
        const frag_ab f = *(const frag_ab*)(featb + (long)sn * 128 + fi);
        #pragma unroll
        for (int j = 0; j < 8; ++j) a[j] += w * b2f((unsigned short)f[j]);
    }
    // reduce s and accumulators over the 4 quarters
    sl += __shfl_xor(sl, 16);
    sl += __shfl_xor(sl, 32);
    #pragma unroll
    for (int j = 0; j < 8; ++j) {
        a[j] += __shfl_xor(a[j], 16);
        a[j] += __shfl_xor(a[j], 32);
    }

    if (lane < 16) {
        const float inv = 1.f / fmaxf(sl, 1e-9f);
        float v[8];
        #pragma unroll
        for (int j = 0; j < 8; ++j) v[j] = a[j] * inv;
        if constexpr (HAS_RES) {
            const frag_ab rr = *(const frag_ab*)(res + (long)node * 128 + fi);
            #pragma unroll
            for (int j = 0; j < 8; ++j) v[j] += b2f((unsigned short)rr[j]);
        }
        #pragma unroll
        for (int t = 0; t < NELU; ++t)
            #pragma unroll
            for (int j = 0; j < 8; ++j)
                v[j] = (v[j] > 0.f) ? v[j] : expm1f(v[j]);
        frag_ab o;
        #pragma unroll
        for (int j = 0; j < 8; ++j) o[j] = f2bf(v[j]);
        *(frag_ab*)(out + (long)node * 128 + fi) = o;
    }
}

// ---- final fused kernel: node_agg1 single-pass (blocks < NODE_BLKS) + e2 ----
// Node branch: half-wave per edge; 24 active lanes x ushort2 cover the padded
// 48-feature row (feature 47 == 0 pad). Score inline per half; s is
// lane-uniform within a half -> total = shfl(s,0)+shfl(s,32).
__global__ __launch_bounds__(256) void final_k(
    const bf16* __restrict__ featb48, const float* __restrict__ el2s,
    const float* __restrict__ er2s,
    const int* __restrict__ loff, const int* __restrict__ bases,
    const int* __restrict__ srcs,
    const bf16* __restrict__ res48, float* __restrict__ logits,
    const int* __restrict__ src, const int* __restrict__ dst,
    float* __restrict__ e2) {
    if (blockIdx.x < NODE_BLKS) {
        const int node = (int)((blockIdx.x * blockDim.x + threadIdx.x) >> 6);
        const int lane = threadIdx.x & 63;
        const int beg = loff[node] + bases[node >> 10];
        const int end = (node == NN - 1) ? NE : loff[node + 1] + bases[(node + 1) >> 10];
        const float ern = er2s[node];

        const int half = lane >> 5;   // 0/1: edge slot
        const int l31 = lane & 31;
        const bool act = l31 < 24;    // 24 lanes x 2 features = 48 (feature 47 = pad)
        const int fi = l31 * 2;

        float a0 = 0.f, a1 = 0.f, sl = 0.f;
        int i = beg + half;
        for (; i + 2 < end; i += 4) {
            const int iB = i + 2;
            const int snA = srcs[i], snB = srcs[iB];
            const float wA = expw(el2s[snA] + ern);
            const float wB = expw(el2s[snB] + ern);
            sl += wA + wB;
            if (act) {
                const ushort2 fA = *(const ushort2*)(featb48 + (long)snA * 48 + fi);
                const ushort2 fB = *(const ushort2*)(featb48 + (long)snB * 48 + fi);
                a0 += wA * b2f(fA.x) + wB * b2f(fB.x);
                a1 += wA * b2f(fA.y) + wB * b2f(fB.y);
            }
        }
        for (; i < end; i += 2) {
            const int sn = srcs[i];
            const float w = expw(el2s[sn] + ern);
            sl += w;
            if (act) {
                const ushort2 f = *(const ushort2*)(featb48 + (long)sn * 48 + fi);
                a0 += w * b2f(f.x);
                a1 += w * b2f(f.y);
            }
        }
        // total s: sl is identical across lanes within a half
        const float s = __shfl(sl, 0) + __shfl(sl, 32);
        a0 += __shfl_xor(a0, 32);
        a1 += __shfl_xor(a1, 32);

        if (lane < 24) {
            const float inv = 1.f / fmaxf(s, 1e-9f);
            const ushort2 rr = *(const ushort2*)(res48 + (long)node * 48 + fi);
            const float v0 = a0 * inv + b2f(rr.x);
            const float v1 = a1 * inv + b2f(rr.y);
            logits[(long)node * NC + fi] = v0;
            if (fi + 1 < NC) logits[(long)node * NC + fi + 1] = v1;
        }
    } else {
        const int e = (blockIdx.x - NODE_BLKS) * 256 + threadIdx.x;  // exact NE
        e2[e] = lrelu(el2s[src[e]] + er2s[dst[e]]);
    }
}

extern "C" void kernel_launch(void* const* d_in, const int* in_sizes, int n_in,
                              void* d_out, int out_size, void* d_ws, size_t ws_size,
                              hipStream_t stream) {
    const float* x     = (const float*)d_in[0];
    const float* W0    = (const float*)d_in[1];
    const float* al0   = (const float*)d_in[2];
    const float* ar0   = (const float*)d_in[3];
    const float* W1    = (const float*)d_in[4];
    const float* resW1 = (const float*)d_in[5];
    const float* al1   = (const float*)d_in[6];
    const float* ar1   = (const float*)d_in[7];
    const float* W2    = (const float*)d_in[8];
    const float* resW2 = (const float*)d_in[9];
    const float* al2   = (const float*)d_in[10];
    const float* ar2   = (const float*)d_in[11];
    const int*   src   = (const int*)d_in[12];
    const int*   dst   = (const int*)d_in[13];

    float* out    = (float*)d_out;
    float* logits = out;                 // [N, 47]
    float* e0     = out + (long)NN * NC; // [E, 4]
    float* e1     = e0 + (long)NE * NH;  // [E, 4]
    float* e2     = e1 + (long)NE * NH;  // [E, 1]

    char* p = (char*)d_ws;
    int* cnt    = (int*)p; p += align256(sizeof(int) * (NN + 64));  // cnt + done ctr
    int* done   = cnt + NN;
    int* loff   = (int*)p; p += align256(sizeof(int) * (NN + 1));
    int* bsum   = (int*)p; p += align256(sizeof(int) * 32);
    int* bases  = (int*)p; p += align256(sizeof(int) * 32);
    int* rank   = (int*)p; p += align256(sizeof(int) * NE);
    int* srcs   = (int*)p; p += align256(sizeof(int) * NE);
    float* el0b = (float*)p; p += align256(sizeof(float) * NN * NH);
    float* er0b = (float*)p; p += align256(sizeof(float) * NN * NH);
    float* el1b = (float*)p; p += align256(sizeof(float) * NN * NH);
    float* er1b = (float*)p; p += align256(sizeof(float) * NN * NH);
    float* el2b = (float*)p; p += align256(sizeof(float) * NN);
    float* er2b = (float*)p; p += align256(sizeof(float) * NN);
    bf16* resb  = (bf16*)p; p += align256(sizeof(bf16) * (long)NN * 128);
    bf16* featb = (bf16*)p; p += align256(sizeof(bf16) * (long)NN * 128);
    bf16* hb    = (bf16*)p; p += align256(sizeof(bf16) * (long)NN * 128);
    bf16* W0t   = (bf16*)p; p += align256(sizeof(bf16) * 144 * 256);
    bf16* W1t   = (bf16*)p; p += align256(sizeof(bf16) * 144 * 128);
    bf16* rW1t  = (bf16*)p; p += align256(sizeof(bf16) * 128 * 128);
    bf16* W2t   = (bf16*)p; p += align256(sizeof(bf16) * 64 * 128);
    bf16* rW2t  = (bf16*)p; p += align256(sizeof(bf16) * 48 * 128);

    const int gemmBlocks = (NN + 63) / 64;   // 469

    // ---- 1: zero cnt+done; 2: prep weights ∥ count+rank ----
    hipMemsetAsync(cnt, 0, sizeof(int) * (NN + 64), stream);
    prep_count<<<dim3(EDGE_BLKS, 6), 256, 0, stream>>>(
        W0, W1, resW1, W2, resW2, al0, ar0, al1, ar1, al2, ar2,
        W0t, W1t, rW1t, W2t, rW2t, dst, cnt, rank);

    // ---- 3: gemm0 ∥ scanA (chunk scans + bases, hidden under layer-0 GEMM) ----
    gemm_mfma<true, 9, 0, NH, 1><<<gemmBlocks + NCHUNKS, 256, 0, stream>>>(
        x, W0t, nullptr, featb, el0b, er0b, nullptr, NN, FIN, 128, gemmBlocks,
        cnt, loff, bsum, bases, done, nullptr, nullptr, nullptr, nullptr, nullptr);

    // ---- 4: fill (atomic-free, rank-based) ----
    fill_k<<<EDGE_BLKS, 256, 0, stream>>>(dst, src, rank, loff, bases, srcs);

    // ---- 5: layer-0 aggregation (single pass) ----
    node_agg4<1, false><<<NODE_BLKS, 256, 0, stream>>>(
        featb, el0b, (const float4*)er0b, loff, bases, srcs, nullptr, hb);

    // ---- 6: gemm1 (dual) ∥ e0 writes ----
    gemm_mfma<false, 9, 8, NH, 2><<<gemmBlocks + EDGE_BLKS, 256, 0, stream>>>(
        hb, W1t, rW1t, featb, el1b, er1b, resb, NN, 128, 128, gemmBlocks,
        nullptr, nullptr, nullptr, nullptr, nullptr,
        (const float4*)el0b, (const float4*)er0b, src, dst, e0);

    // ---- 7: layer-1 aggregation (single pass) ----
    node_agg4<2, true><<<NODE_BLKS, 256, 0, stream>>>(
        featb, el1b, (const float4*)er1b, loff, bases, srcs, resb, hb);

    // ---- 8: gemm2 (dual, padded M=48) ∥ e1 writes ----
    // W2t: rows 0..46 = W2^T, row 47 = 0, rows 48/49 = W2·al2 / W2·ar2.
    // featb/resb written at stride 48 (col 47 exactly 0 from zero weight rows).
    gemm_mfma<false, 4, 3, 1, 2><<<gemmBlocks + EDGE_BLKS, 256, 0, stream>>>(
        hb, W2t, rW2t, featb, el2b, er2b, resb, NN, 128, 48, gemmBlocks,
        nullptr, nullptr, nullptr, nullptr, nullptr,
        (const float4*)el1b, (const float4*)er1b, src, dst, e1);

    // ---- 9: node_agg1 single-pass (logits) ∥ e2 writes ----
    final_k<<<NODE_BLKS + EDGE_BLKS, 256, 0, stream>>>(
        featb, el2b, er2b, loff, bases, srcs, resb, logits, src, dst, e2);
}